// Round 19
// baseline (217.593 us; speedup 1.0000x reference)
//
#include <hip/hip_runtime.h>

#define NN 256
#define DIN 32
#define DD 64
#define D2 128
#define RTOT 4096      // BB*NN rows
#define GBD 256        // d/fin blocks
#define RPB 16         // rows per d block
#define GBC 512        // bc blocks
#define RPC 8          // rows per bc block
#define AST 32         // acc slot stride in floats (128 B line per channel)

typedef float f32x4 __attribute__((ext_vector_type(4)));
typedef float f32x2 __attribute__((ext_vector_type(2)));

__device__ __forceinline__ void fma4(f32x4& o, float s, const f32x4 w) {
  o[0] = fmaf(s, w[0], o[0]); o[1] = fmaf(s, w[1], o[1]);
  o[2] = fmaf(s, w[2], o[2]); o[3] = fmaf(s, w[3], o[3]);
}

__device__ __forceinline__ unsigned f2b(float f) {
  unsigned u = __float_as_uint(f);
  return (u + 0x7FFFu + ((u >> 16) & 1u)) >> 16;
}
__device__ __forceinline__ float b2f(unsigned short h) {
  return __uint_as_float(((unsigned)h) << 16);
}

// x(bf16) = fea @ encW + encb ; first 48 blocks zero the acc region
__global__ __launch_bounds__(256) void enc_kernel(
    const float* __restrict__ fea, const float* __restrict__ W,
    const float* __restrict__ bias, unsigned short* __restrict__ xb16,
    float* __restrict__ accz) {
  if (blockIdx.x < 48) {
#pragma unroll
    for (int i = 0; i < 4; ++i)
      accz[blockIdx.x * 1024 + i * 256 + threadIdx.x] = 0.f;
  }
  int g = blockIdx.x * 256 + threadIdx.x;
  int r = g >> 5, c0 = (g & 31) * 2;
  const float* fr = fea + r * DIN;
  float a0 = bias[c0], a1 = bias[c0 + 1];
#pragma unroll
  for (int k = 0; k < DIN; ++k) {
    float fv = fr[k];
    a0 = fmaf(fv, W[k * DD + c0], a0);
    a1 = fmaf(fv, W[k * DD + c0 + 1], a1);
  }
  ((unsigned*)xb16)[g] = f2b(a0) | (f2b(a1) << 16);
}

// bc (r18): whole-batch Y (bf16) staged in LDS; ballot agg; MLP1 global-W1.
__global__ __launch_bounds__(256, 4) void bc_kernel(
    const float* __restrict__ adj, const unsigned short* __restrict__ xb16,
    const float* __restrict__ bondW, const float* __restrict__ epsp,
    const float* __restrict__ W1, const float* __restrict__ b1,
    const float* __restrict__ gbnp, const float* __restrict__ bbnp,
    const float* __restrict__ acc2p, int apply_bn,
    unsigned short* __restrict__ h1b, float* __restrict__ acc1) {
  __shared__ unsigned short sYb[NN * DD];
  __shared__ float sh[RPC * DD];
  __shared__ float sSB[2 * DD];
  float* pst = (float*)sYb;
  const int tid = threadIdx.x;
  const int sbid = ((blockIdx.x & 7) << 6) + (blockIdx.x >> 3);
  const int lane = tid & 63, wv = tid >> 6;
  const int b = sbid >> 5;
  const int r0 = (sbid & 31) * RPC;

  if (apply_bn && tid < DD) {
    float s = acc2p[tid * AST], q = acc2p[(64 + tid) * AST];
    float mean = s * (1.f / RTOT);
    float var = fmaf(-mean, mean, q * (1.f / RTOT));
    float sc = gbnp[tid] * rsqrtf(var + 1e-5f);
    sSB[tid] = sc;
    sSB[64 + tid] = fmaf(-mean, sc, bbnp[tid]);
  }
  __syncthreads();

  const unsigned short* xb = xb16 + (size_t)b * NN * DD;

  float a[2][4];
#pragma unroll
  for (int rr = 0; rr < 2; ++rr) {
    const float* adjr = adj + ((size_t)b * NN + r0 + wv * 2 + rr) * NN + lane;
#pragma unroll
    for (int ck = 0; ck < 4; ++ck) a[rr][ck] = adjr[ck * 64];
  }
  unsigned short xo[2];
#pragma unroll
  for (int rr = 0; rr < 2; ++rr)
    xo[rr] = xb[(size_t)(r0 + wv * 2 + rr) * DD + lane];
  uint4 yv[8];
  {
    const uint4* xb4 = (const uint4*)xb;
#pragma unroll
    for (int k = 0; k < 8; ++k) yv[k] = xb4[tid + k * 256];
  }

  unsigned long long m[2][4];
#pragma unroll
  for (int rr = 0; rr < 2; ++rr)
#pragma unroll
    for (int ck = 0; ck < 4; ++ck) m[rr][ck] = __ballot(a[rr][ck] != 0.f);

  {
    const int d0 = (tid & 7) * 8;
    float BW8[8], S8[8], B8[8];
#pragma unroll
    for (int j = 0; j < 8; ++j) {
      BW8[j] = bondW[d0 + j];
      S8[j] = apply_bn ? sSB[d0 + j] : 0.f;
      B8[j] = apply_bn ? sSB[64 + d0 + j] : 0.f;
    }
    uint4* sy4 = (uint4*)sYb;
#pragma unroll
    for (int k = 0; k < 8; ++k) {
      unsigned w[4] = {yv[k].x, yv[k].y, yv[k].z, yv[k].w};
      unsigned o[4];
#pragma unroll
      for (int q = 0; q < 4; ++q) {
        float f0 = __uint_as_float(w[q] << 16);
        float f1 = __uint_as_float(w[q] & 0xFFFF0000u);
        if (apply_bn) {
          f0 = fmaxf(fmaf(f0, S8[2 * q], B8[2 * q]), 0.f);
          f1 = fmaxf(fmaf(f1, S8[2 * q + 1], B8[2 * q + 1]), 0.f);
        }
        f0 = fmaxf(f0 + BW8[2 * q], 0.f);
        f1 = fmaxf(f1 + BW8[2 * q + 1], 0.f);
        o[q] = f2b(f0) | (f2b(f1) << 16);
      }
      sy4[tid + k * 256] = make_uint4(o[0], o[1], o[2], o[3]);
    }
  }
  __syncthreads();

  {
    float S = 0.f, Bv = 0.f;
    if (apply_bn) { S = sSB[lane]; Bv = sSB[64 + lane]; }
    float epv = 1.f + epsp[0];
#pragma unroll
    for (int rr = 0; rr < 2; ++rr) {
      float av = 0.f;
#pragma unroll
      for (int ck = 0; ck < 4; ++ck) {
        unsigned long long mm = m[rr][ck];
        const unsigned short* yb = sYb + ck * 64 * DD + lane;
        while (mm) {
          unsigned short v[8]; bool hb[8];
#pragma unroll
          for (int u = 0; u < 8; ++u) {
            bool ok = mm != 0ull;
            int j = ok ? (int)__builtin_ctzll(mm) : 0;
            mm &= mm - 1;
            hb[u] = ok;
            v[u] = yb[j * DD];
          }
#pragma unroll
          for (int u = 0; u < 8; ++u) av += hb[u] ? b2f(v[u]) : 0.f;
        }
      }
      float xv = b2f(xo[rr]);
      if (apply_bn) xv = fmaxf(fmaf(xv, S, Bv), 0.f);
      sh[(wv * 2 + rr) * DD + lane] = fmaf(epv, xv, av);
    }
  }
  __syncthreads();

  {
    int row = tid >> 5, c0 = (tid & 31) * 4;
    f32x4 o = *(const f32x4*)&b1[c0];
#pragma unroll 4
    for (int d = 0; d < DD; d += 4) {
      f32x4 hv = *(const f32x4*)&sh[row * DD + d];
      f32x4 w0 = *(const f32x4*)&W1[(d + 0) * D2 + c0];
      f32x4 w1 = *(const f32x4*)&W1[(d + 1) * D2 + c0];
      f32x4 w2 = *(const f32x4*)&W1[(d + 2) * D2 + c0];
      f32x4 w3 = *(const f32x4*)&W1[(d + 3) * D2 + c0];
      fma4(o, hv[0], w0); fma4(o, hv[1], w1); fma4(o, hv[2], w2); fma4(o, hv[3], w3);
    }
    uint2 hp;
    hp.x = f2b(o[0]) | (f2b(o[1]) << 16);
    hp.y = f2b(o[2]) | (f2b(o[3]) << 16);
    *(uint2*)&h1b[(size_t)(b * NN + r0 + row) * D2 + c0] = hp;
    *(f32x4*)&pst[row * D2 + c0] = o;
    *(f32x4*)&pst[RPC * D2 + row * D2 + c0] = o * o;
  }
  __syncthreads();
  if (tid < D2) {
    float s = 0.f, q = 0.f;
#pragma unroll
    for (int g = 0; g < RPC; ++g) {
      s += pst[g * D2 + tid];
      q += pst[RPC * D2 + g * D2 + tid];
    }
    atomicAdd(acc1 + tid * AST, s);
    atomicAdd(acc1 + (128 + tid) * AST, q);
  }
}

// ===== PROBE: bc body looped 10x into dummy buffers (rotating row slice) =====
__global__ __launch_bounds__(256, 4) void bc_probe(
    const float* __restrict__ adj, const unsigned short* __restrict__ xb16,
    const float* __restrict__ bondW, const float* __restrict__ epsp,
    const float* __restrict__ W1, const float* __restrict__ b1,
    unsigned short* __restrict__ h1b, float* __restrict__ acc1) {
  __shared__ unsigned short sYb[NN * DD];
  __shared__ float sh[RPC * DD];
  float* pst = (float*)sYb;
  const int tid = threadIdx.x;
  const int sbid = ((blockIdx.x & 7) << 6) + (blockIdx.x >> 3);
  const int lane = tid & 63, wv = tid >> 6;
  const int b = sbid >> 5;
  const unsigned short* xb = xb16 + (size_t)b * NN * DD;

  for (int it = 0; it < 10; ++it) {
    __syncthreads();
    const int r0 = (((sbid & 31) + it) & 31) * RPC;

    float a[2][4];
#pragma unroll
    for (int rr = 0; rr < 2; ++rr) {
      const float* adjr = adj + ((size_t)b * NN + r0 + wv * 2 + rr) * NN + lane;
#pragma unroll
      for (int ck = 0; ck < 4; ++ck) a[rr][ck] = adjr[ck * 64];
    }
    unsigned short xo[2];
#pragma unroll
    for (int rr = 0; rr < 2; ++rr)
      xo[rr] = xb[(size_t)(r0 + wv * 2 + rr) * DD + lane];
    uint4 yv[8];
    {
      const uint4* xb4 = (const uint4*)xb;
#pragma unroll
      for (int k = 0; k < 8; ++k) yv[k] = xb4[tid + k * 256];
    }
    unsigned long long m[2][4];
#pragma unroll
    for (int rr = 0; rr < 2; ++rr)
#pragma unroll
      for (int ck = 0; ck < 4; ++ck) m[rr][ck] = __ballot(a[rr][ck] != 0.f);

    {
      const int d0 = (tid & 7) * 8;
      float BW8[8];
#pragma unroll
      for (int j = 0; j < 8; ++j) BW8[j] = bondW[d0 + j];
      uint4* sy4 = (uint4*)sYb;
#pragma unroll
      for (int k = 0; k < 8; ++k) {
        unsigned w[4] = {yv[k].x, yv[k].y, yv[k].z, yv[k].w};
        unsigned o[4];
#pragma unroll
        for (int q = 0; q < 4; ++q) {
          float f0 = __uint_as_float(w[q] << 16);
          float f1 = __uint_as_float(w[q] & 0xFFFF0000u);
          f0 = fmaxf(f0 + BW8[2 * q], 0.f);
          f1 = fmaxf(f1 + BW8[2 * q + 1], 0.f);
          o[q] = f2b(f0) | (f2b(f1) << 16);
        }
        sy4[tid + k * 256] = make_uint4(o[0], o[1], o[2], o[3]);
      }
    }
    __syncthreads();

    {
      float epv = 1.f + epsp[0];
#pragma unroll
      for (int rr = 0; rr < 2; ++rr) {
        float av = 0.f;
#pragma unroll
        for (int ck = 0; ck < 4; ++ck) {
          unsigned long long mm = m[rr][ck];
          const unsigned short* yb = sYb + ck * 64 * DD + lane;
          while (mm) {
            unsigned short v[8]; bool hb[8];
#pragma unroll
            for (int u = 0; u < 8; ++u) {
              bool ok = mm != 0ull;
              int j = ok ? (int)__builtin_ctzll(mm) : 0;
              mm &= mm - 1;
              hb[u] = ok;
              v[u] = yb[j * DD];
            }
#pragma unroll
            for (int u = 0; u < 8; ++u) av += hb[u] ? b2f(v[u]) : 0.f;
          }
        }
        sh[(wv * 2 + rr) * DD + lane] = fmaf(epv, b2f(xo[rr]), av);
      }
    }
    __syncthreads();

    {
      int row = tid >> 5, c0 = (tid & 31) * 4;
      f32x4 o = *(const f32x4*)&b1[c0];
#pragma unroll 4
      for (int d = 0; d < DD; d += 4) {
        f32x4 hv = *(const f32x4*)&sh[row * DD + d];
        f32x4 w0 = *(const f32x4*)&W1[(d + 0) * D2 + c0];
        f32x4 w1 = *(const f32x4*)&W1[(d + 1) * D2 + c0];
        f32x4 w2 = *(const f32x4*)&W1[(d + 2) * D2 + c0];
        f32x4 w3 = *(const f32x4*)&W1[(d + 3) * D2 + c0];
        fma4(o, hv[0], w0); fma4(o, hv[1], w1); fma4(o, hv[2], w2); fma4(o, hv[3], w3);
      }
      uint2 hp;
      hp.x = f2b(o[0]) | (f2b(o[1]) << 16);
      hp.y = f2b(o[2]) | (f2b(o[3]) << 16);
      *(uint2*)&h1b[(size_t)(b * NN + r0 + row) * D2 + c0] = hp;
      *(f32x4*)&pst[row * D2 + c0] = o;
      *(f32x4*)&pst[RPC * D2 + row * D2 + c0] = o * o;
    }
    __syncthreads();
    if (tid < D2) {
      float s = 0.f, q = 0.f;
#pragma unroll
      for (int g = 0; g < RPC; ++g) {
        s += pst[g * D2 + tid];
        q += pst[RPC * D2 + g * D2 + tid];
      }
      atomicAdd(acc1 + tid * AST, s);
      atomicAdd(acc1 + (128 + tid) * AST, q);
    }
  }
}

// d (r18): 256 blocks x 16 rows, LDS W2
__global__ __launch_bounds__(256) void d_kernel(
    const unsigned short* __restrict__ h1b, const float* __restrict__ W2,
    const float* __restrict__ b2, const float* __restrict__ g1,
    const float* __restrict__ be1, unsigned short* __restrict__ xb16,
    const float* __restrict__ acc1, float* __restrict__ acc2) {
  __shared__ float sW2[D2 * DD];
  __shared__ float sh1[RPB][D2 + 4];
  __shared__ float sS[D2], sB[D2];
  __shared__ float pst[2 * 8 * DD];
  int tid = threadIdx.x, bid = blockIdx.x;

  {
    const f32x4* w4 = (const f32x4*)W2;
    f32x4* s4 = (f32x4*)sW2;
#pragma unroll
    for (int i = 0; i < 8; ++i) s4[tid + i * 256] = w4[tid + i * 256];
  }
  if (tid < D2) {
    float mean = acc1[tid * AST] * (1.f / RTOT);
    float var = fmaf(-mean, mean, acc1[(128 + tid) * AST] * (1.f / RTOT));
    float sc = g1[tid] * rsqrtf(var + 1e-5f);
    sS[tid] = sc;
    sB[tid] = fmaf(-mean, sc, be1[tid]);
  }
  __syncthreads();
  {
    uint4 hv = ((const uint4*)(h1b + (size_t)bid * RPB * D2))[tid];
    int row = tid >> 4, cb = (tid & 15) * 8;
    unsigned w[4] = {hv.x, hv.y, hv.z, hv.w};
#pragma unroll
    for (int q = 0; q < 4; ++q) {
      float f0 = __uint_as_float(w[q] << 16);
      float f1 = __uint_as_float(w[q] & 0xFFFF0000u);
      int c = cb + 2 * q;
      sh1[row][c]     = fmaxf(fmaf(f0, sS[c],     sB[c]),     0.f);
      sh1[row][c + 1] = fmaxf(fmaf(f1, sS[c + 1], sB[c + 1]), 0.f);
    }
  }
  __syncthreads();

  float* pssum = pst;
  float* pssq  = pst + 8 * DD;
  if (tid < 128) {
    int rg = tid >> 4;
    int c0 = (tid & 15) * 4;
    f32x4 bv = *(const f32x4*)&b2[c0];
    f32x4 o0 = bv, o1 = bv;
    for (int c = 0; c < D2; c += 4) {
      f32x4 s0 = *(const f32x4*)&sh1[rg * 2 + 0][c];
      f32x4 s1 = *(const f32x4*)&sh1[rg * 2 + 1][c];
      f32x4 w0 = *(const f32x4*)&sW2[(c + 0) * DD + c0];
      f32x4 w1 = *(const f32x4*)&sW2[(c + 1) * DD + c0];
      f32x4 w2 = *(const f32x4*)&sW2[(c + 2) * DD + c0];
      f32x4 w3 = *(const f32x4*)&sW2[(c + 3) * DD + c0];
      fma4(o0, s0[0], w0); fma4(o0, s0[1], w1); fma4(o0, s0[2], w2); fma4(o0, s0[3], w3);
      fma4(o1, s1[0], w0); fma4(o1, s1[1], w1); fma4(o1, s1[2], w2); fma4(o1, s1[3], w3);
    }
    size_t gr = (size_t)(bid * RPB + rg * 2) * DD + c0;
    uint2 p0, p1;
    p0.x = f2b(o0[0]) | (f2b(o0[1]) << 16);
    p0.y = f2b(o0[2]) | (f2b(o0[3]) << 16);
    p1.x = f2b(o1[0]) | (f2b(o1[1]) << 16);
    p1.y = f2b(o1[2]) | (f2b(o1[3]) << 16);
    *(uint2*)&xb16[gr] = p0;
    *(uint2*)&xb16[gr + DD] = p1;
    *(f32x4*)&pssum[rg * DD + c0] = o0 + o1;
    *(f32x4*)&pssq[rg * DD + c0] = o0 * o0 + o1 * o1;
  }
  __syncthreads();
  if (tid < DD) {
    float s = 0.f, q = 0.f;
#pragma unroll
    for (int g = 0; g < 8; ++g) { s += pssum[g * DD + tid]; q += pssq[g * DD + tid]; }
    atomicAdd(acc2 + tid * AST, s);
    atomicAdd(acc2 + (64 + tid) * AST, q);
  }
}

// ===== PROBE: d body looped 10x into dummy buffers (rotating block) =====
__global__ __launch_bounds__(256) void d_probe(
    const unsigned short* __restrict__ h1b, const float* __restrict__ W2,
    const float* __restrict__ b2, const float* __restrict__ g1,
    const float* __restrict__ be1, unsigned short* __restrict__ xdum,
    const float* __restrict__ acc1, float* __restrict__ acc2) {
  __shared__ float sW2[D2 * DD];
  __shared__ float sh1[RPB][D2 + 4];
  __shared__ float sS[D2], sB[D2];
  __shared__ float pst[2 * 8 * DD];
  int tid = threadIdx.x;

  for (int it = 0; it < 10; ++it) {
    __syncthreads();
    int bid = (blockIdx.x + it * 16) & 255;
    {
      const f32x4* w4 = (const f32x4*)W2;
      f32x4* s4 = (f32x4*)sW2;
#pragma unroll
      for (int i = 0; i < 8; ++i) s4[tid + i * 256] = w4[tid + i * 256];
    }
    if (tid < D2) {
      float mean = acc1[tid * AST] * (1.f / RTOT);
      float var = fmaf(-mean, mean, acc1[(128 + tid) * AST] * (1.f / RTOT));
      float sc = g1[tid] * rsqrtf(var + 1e-5f);
      sS[tid] = sc;
      sB[tid] = fmaf(-mean, sc, be1[tid]);
    }
    __syncthreads();
    {
      uint4 hv = ((const uint4*)(h1b + (size_t)bid * RPB * D2))[tid];
      int row = tid >> 4, cb = (tid & 15) * 8;
      unsigned w[4] = {hv.x, hv.y, hv.z, hv.w};
#pragma unroll
      for (int q = 0; q < 4; ++q) {
        float f0 = __uint_as_float(w[q] << 16);
        float f1 = __uint_as_float(w[q] & 0xFFFF0000u);
        int c = cb + 2 * q;
        sh1[row][c]     = fmaxf(fmaf(f0, sS[c],     sB[c]),     0.f);
        sh1[row][c + 1] = fmaxf(fmaf(f1, sS[c + 1], sB[c + 1]), 0.f);
      }
    }
    __syncthreads();
    float* pssum = pst;
    float* pssq  = pst + 8 * DD;
    if (tid < 128) {
      int rg = tid >> 4;
      int c0 = (tid & 15) * 4;
      f32x4 bv = *(const f32x4*)&b2[c0];
      f32x4 o0 = bv, o1 = bv;
      for (int c = 0; c < D2; c += 4) {
        f32x4 s0 = *(const f32x4*)&sh1[rg * 2 + 0][c];
        f32x4 s1 = *(const f32x4*)&sh1[rg * 2 + 1][c];
        f32x4 w0 = *(const f32x4*)&sW2[(c + 0) * DD + c0];
        f32x4 w1 = *(const f32x4*)&sW2[(c + 1) * DD + c0];
        f32x4 w2 = *(const f32x4*)&sW2[(c + 2) * DD + c0];
        f32x4 w3 = *(const f32x4*)&sW2[(c + 3) * DD + c0];
        fma4(o0, s0[0], w0); fma4(o0, s0[1], w1); fma4(o0, s0[2], w2); fma4(o0, s0[3], w3);
        fma4(o1, s1[0], w0); fma4(o1, s1[1], w1); fma4(o1, s1[2], w2); fma4(o1, s1[3], w3);
      }
      size_t gr = (size_t)(bid * RPB + rg * 2) * DD + c0;
      uint2 p0, p1;
      p0.x = f2b(o0[0]) | (f2b(o0[1]) << 16);
      p0.y = f2b(o0[2]) | (f2b(o0[3]) << 16);
      p1.x = f2b(o1[0]) | (f2b(o1[1]) << 16);
      p1.y = f2b(o1[2]) | (f2b(o1[3]) << 16);
      *(uint2*)&xdum[gr] = p0;
      *(uint2*)&xdum[gr + DD] = p1;
      *(f32x4*)&pssum[rg * DD + c0] = o0 + o1;
      *(f32x4*)&pssq[rg * DD + c0] = o0 * o0 + o1 * o1;
    }
    __syncthreads();
    if (tid < DD) {
      float s = 0.f, q = 0.f;
#pragma unroll
      for (int g = 0; g < 8; ++g) { s += pssum[g * DD + tid]; q += pssq[g * DD + tid]; }
      atomicAdd(acc2 + tid * AST, s);
      atomicAdd(acc2 + (64 + tid) * AST, q);
    }
  }
}

// fin: BN2 (no relu) from padded acc, bf16 h2 -> fp32 out
__global__ __launch_bounds__(256) void fin_kernel(
    const unsigned short* __restrict__ xb16, const float* __restrict__ gbn,
    const float* __restrict__ bbn, const float* __restrict__ acc2,
    float* __restrict__ outp) {
  __shared__ float sS2[DD], sB2[DD];
  int tid = threadIdx.x, bid = blockIdx.x;
  if (tid < 64) {
    float mean = acc2[tid * AST] * (1.f / RTOT);
    float var = fmaf(-mean, mean, acc2[(64 + tid) * AST] * (1.f / RTOT));
    float sc = gbn[tid] * rsqrtf(var + 1e-5f);
    sS2[tid] = sc;
    sB2[tid] = fmaf(-mean, sc, bbn[tid]);
  }
  __syncthreads();
  {
    int g = bid * 256 + tid;
    uint2 v = ((const uint2*)xb16)[g];
    int e0 = g * 4;
    int c0 = e0 & 63;
    f32x4 o;
    o[0] = fmaf(__uint_as_float(v.x << 16),         sS2[c0],     sB2[c0]);
    o[1] = fmaf(__uint_as_float(v.x & 0xFFFF0000u), sS2[c0 + 1], sB2[c0 + 1]);
    o[2] = fmaf(__uint_as_float(v.y << 16),         sS2[c0 + 2], sB2[c0 + 2]);
    o[3] = fmaf(__uint_as_float(v.y & 0xFFFF0000u), sS2[c0 + 3], sB2[c0 + 3]);
    *(f32x4*)&outp[e0] = o;
  }
}

extern "C" void kernel_launch(void* const* d_in, const int* in_sizes, int n_in,
                              void* d_out, int out_size, void* d_ws, size_t ws_size,
                              hipStream_t stream) {
  const float* fea  = (const float*)d_in[0];
  const float* adj  = (const float*)d_in[1];
  const float* encW = (const float*)d_in[2];
  const float* encb = (const float*)d_in[3];
  const float* bondW= (const float*)d_in[4];
  const float* eps  = (const float*)d_in[5];
  const float* W1   = (const float*)d_in[6];
  const float* b1   = (const float*)d_in[7];
  const float* g1   = (const float*)d_in[8];
  const float* be1  = (const float*)d_in[9];
  const float* W2   = (const float*)d_in[10];
  const float* b2   = (const float*)d_in[11];
  const float* gbn  = (const float*)d_in[12];
  const float* bbn  = (const float*)d_in[13];
  float* out = (float*)d_out;
  float* ws  = (float*)d_ws;

  unsigned short* xb16 = (unsigned short*)ws;              // 262144 bf16
  unsigned short* h1b  = (unsigned short*)(ws + 131072);   // 524288 bf16
  float* acc = ws + 393216;                                // 49152 floats
  unsigned short* dum_h1 = (unsigned short*)(ws + 442368); // 524288 bf16
  float* dum_acc = ws + 704512;                            // 16384 floats
  unsigned short* dum_x  = (unsigned short*)(ws + 720896); // 262144 bf16

  enc_kernel<<<512, 256, 0, stream>>>(fea, encW, encb, xb16, acc);
  for (int l = 0; l < 3; ++l) {
    float* accl = acc + (size_t)l * 512 * AST;
    bc_kernel<<<GBC, 256, 0, stream>>>(
        adj, xb16, bondW + l * DD, eps + l, W1 + l * DD * D2, b1 + l * D2,
        l ? gbn + (l - 1) * DD : gbn, l ? bbn + (l - 1) * DD : bbn,
        l ? acc + (size_t)(l - 1) * 512 * AST + 256 * AST : acc,
        l > 0 ? 1 : 0, h1b, accl);
    d_kernel<<<GBD, 256, 0, stream>>>(h1b, W2 + l * D2 * DD, b2 + l * DD,
                                      g1 + l * D2, be1 + l * D2, xb16,
                                      accl, accl + 256 * AST);
  }
  fin_kernel<<<256, 256, 0, stream>>>(xb16, gbn + 2 * DD, bbn + 2 * DD,
                                      acc + (size_t)2 * 512 * AST + 256 * AST, out);

  // ---- instrumentation probes (write only scratch; output unaffected) ----
  bc_probe<<<GBC, 256, 0, stream>>>(adj, xb16, bondW, eps, W1, b1,
                                    dum_h1, dum_acc);
  d_probe<<<GBD, 256, 0, stream>>>(h1b, W2, b2, g1, be1, dum_x,
                                   acc, dum_acc + 8192);
}

// Round 20
// 94.054 us; speedup vs baseline: 2.3135x; 2.3135x over previous
//
#include <hip/hip_runtime.h>

#define NN 256
#define DIN 32
#define DD 64
#define D2 128
#define RTOT 4096      // BB*NN rows
#define GBD 256        // d/fin blocks
#define RPB 16         // rows per d block
#define GBC 512        // bc blocks (512 threads, 8 rows each)
#define RPC 8          // rows per bc block
#define AST 32         // acc slot stride in floats (128 B line per channel)

typedef float f32x4 __attribute__((ext_vector_type(4)));
typedef float f32x2 __attribute__((ext_vector_type(2)));

__device__ __forceinline__ void fma4(f32x4& o, float s, const f32x4 w) {
  o[0] = fmaf(s, w[0], o[0]); o[1] = fmaf(s, w[1], o[1]);
  o[2] = fmaf(s, w[2], o[2]); o[3] = fmaf(s, w[3], o[3]);
}

__device__ __forceinline__ unsigned f2b(float f) {
  unsigned u = __float_as_uint(f);
  return (u + 0x7FFFu + ((u >> 16) & 1u)) >> 16;
}
__device__ __forceinline__ float b2f(unsigned short h) {
  return __uint_as_float(((unsigned)h) << 16);
}

// x(bf16) = fea @ encW + encb ; first 48 blocks zero the acc region
__global__ __launch_bounds__(256) void enc_kernel(
    const float* __restrict__ fea, const float* __restrict__ W,
    const float* __restrict__ bias, unsigned short* __restrict__ xb16,
    float* __restrict__ accz) {
  if (blockIdx.x < 48) {
#pragma unroll
    for (int i = 0; i < 4; ++i)
      accz[blockIdx.x * 1024 + i * 256 + threadIdx.x] = 0.f;
  }
  int g = blockIdx.x * 256 + threadIdx.x;
  int r = g >> 5, c0 = (g & 31) * 2;
  const float* fr = fea + r * DIN;
  float a0 = bias[c0], a1 = bias[c0 + 1];
#pragma unroll
  for (int k = 0; k < DIN; ++k) {
    float fv = fr[k];
    a0 = fmaf(fv, W[k * DD + c0], a0);
    a1 = fmaf(fv, W[k * DD + c0 + 1], a1);
  }
  ((unsigned*)xb16)[g] = f2b(a0) | (f2b(a1) << 16);
}

// bc: 512 threads (8 waves, wave = 1 row). Whole-batch Y (bf16) in LDS;
// ballot agg; MLP1 global-W1 -> h1 (bf16); padded fp32 BN1 stats.
// 2 blocks/CU -> 16 waves/CU (2x the 256-thread version's occupancy).
__global__ __launch_bounds__(512) void bc_kernel(
    const float* __restrict__ adj, const unsigned short* __restrict__ xb16,
    const float* __restrict__ bondW, const float* __restrict__ epsp,
    const float* __restrict__ W1, const float* __restrict__ b1,
    const float* __restrict__ gbnp, const float* __restrict__ bbnp,
    const float* __restrict__ acc2p, int apply_bn,
    unsigned short* __restrict__ h1b, float* __restrict__ acc1) {
  __shared__ unsigned short sYb[NN * DD];  // 32 KB; pst overlay after agg
  __shared__ float sh[RPC * DD];           // 2 KB
  __shared__ float sSB[2 * DD];            // 0.5 KB
  float* pst = (float*)sYb;                // 2*RPC*D2 = 2048 floats
  const int tid = threadIdx.x;
  const int sbid = ((blockIdx.x & 7) << 6) + (blockIdx.x >> 3);  // XCD affinity
  const int lane = tid & 63, wv = tid >> 6;   // wv 0..7 = row
  const int b = sbid >> 5;
  const int r0 = (sbid & 31) * RPC;

  if (apply_bn && tid < DD) {
    float s = acc2p[tid * AST], q = acc2p[(64 + tid) * AST];
    float mean = s * (1.f / RTOT);
    float var = fmaf(-mean, mean, q * (1.f / RTOT));
    float sc = gbnp[tid] * rsqrtf(var + 1e-5f);
    sSB[tid] = sc;
    sSB[64 + tid] = fmaf(-mean, sc, bbnp[tid]);
  }
  __syncthreads();

  const unsigned short* xb = xb16 + (size_t)b * NN * DD;

  // ---- issue ALL global reads in one burst ----
  float a4[4];
  {
    const float* adjr = adj + ((size_t)b * NN + r0 + wv) * NN + lane;
#pragma unroll
    for (int ck = 0; ck < 4; ++ck) a4[ck] = adjr[ck * 64];
  }
  unsigned short xo = xb[(size_t)(r0 + wv) * DD + lane];
  uint4 yv[4];
  {
    const uint4* xb4 = (const uint4*)xb;
#pragma unroll
    for (int k = 0; k < 4; ++k) yv[k] = xb4[tid + k * 512];
  }

  unsigned long long m[4];
#pragma unroll
  for (int ck = 0; ck < 4; ++ck) m[ck] = __ballot(a4[ck] != 0.f);

  // ---- transform + store Y to LDS as bf16 (one vmcnt drain) ----
  {
    const int d0 = (tid & 7) * 8;
    float BW8[8], S8[8], B8[8];
#pragma unroll
    for (int j = 0; j < 8; ++j) {
      BW8[j] = bondW[d0 + j];
      S8[j] = apply_bn ? sSB[d0 + j] : 0.f;
      B8[j] = apply_bn ? sSB[64 + d0 + j] : 0.f;
    }
    uint4* sy4 = (uint4*)sYb;
#pragma unroll
    for (int k = 0; k < 4; ++k) {
      unsigned w[4] = {yv[k].x, yv[k].y, yv[k].z, yv[k].w};
      unsigned o[4];
#pragma unroll
      for (int q = 0; q < 4; ++q) {
        float f0 = __uint_as_float(w[q] << 16);
        float f1 = __uint_as_float(w[q] & 0xFFFF0000u);
        if (apply_bn) {
          f0 = fmaxf(fmaf(f0, S8[2 * q], B8[2 * q]), 0.f);
          f1 = fmaxf(fmaf(f1, S8[2 * q + 1], B8[2 * q + 1]), 0.f);
        }
        f0 = fmaxf(f0 + BW8[2 * q], 0.f);
        f1 = fmaxf(f1 + BW8[2 * q + 1], 0.f);
        o[q] = f2b(f0) | (f2b(f1) << 16);
      }
      sy4[tid + k * 512] = make_uint4(o[0], o[1], o[2], o[3]);
    }
  }
  __syncthreads();

  // ---- agg: wave's single row, 8-batched bf16 LDS gathers ----
  {
    float av = 0.f;
#pragma unroll
    for (int ck = 0; ck < 4; ++ck) {
      unsigned long long mm = m[ck];
      const unsigned short* yb = sYb + ck * 64 * DD + lane;
      while (mm) {
        unsigned short v[8]; bool hb[8];
#pragma unroll
        for (int u = 0; u < 8; ++u) {
          bool ok = mm != 0ull;
          int j = ok ? (int)__builtin_ctzll(mm) : 0;
          mm &= mm - 1;
          hb[u] = ok;
          v[u] = yb[j * DD];
        }
#pragma unroll
        for (int u = 0; u < 8; ++u) av += hb[u] ? b2f(v[u]) : 0.f;
      }
    }
    float xv = b2f(xo);
    if (apply_bn) xv = fmaxf(fmaf(xv, sSB[lane], sSB[64 + lane]), 0.f);
    sh[wv * DD + lane] = fmaf(1.f + epsp[0], xv, av);
  }
  __syncthreads();    // all sYb reads done; pst overlay safe

  // ---- MLP1: 8x128 tile, thread = 1 row x 2 cols (f32x2), W1 from global ----
  {
    int row = tid >> 6, c0 = (tid & 63) * 2;
    f32x2 o = *(const f32x2*)&b1[c0];
#pragma unroll 4
    for (int d = 0; d < DD; d += 4) {
      f32x4 hv = *(const f32x4*)&sh[row * DD + d];
      f32x2 w0 = *(const f32x2*)&W1[(d + 0) * D2 + c0];
      f32x2 w1 = *(const f32x2*)&W1[(d + 1) * D2 + c0];
      f32x2 w2 = *(const f32x2*)&W1[(d + 2) * D2 + c0];
      f32x2 w3 = *(const f32x2*)&W1[(d + 3) * D2 + c0];
      o[0] = fmaf(hv[0], w0[0], o[0]); o[1] = fmaf(hv[0], w0[1], o[1]);
      o[0] = fmaf(hv[1], w1[0], o[0]); o[1] = fmaf(hv[1], w1[1], o[1]);
      o[0] = fmaf(hv[2], w2[0], o[0]); o[1] = fmaf(hv[2], w2[1], o[1]);
      o[0] = fmaf(hv[3], w3[0], o[0]); o[1] = fmaf(hv[3], w3[1], o[1]);
    }
    *(unsigned*)&h1b[(size_t)(b * NN + r0 + row) * D2 + c0] =
        f2b(o[0]) | (f2b(o[1]) << 16);
    *(f32x2*)&pst[row * D2 + c0] = o;
    f32x2 oq; oq[0] = o[0] * o[0]; oq[1] = o[1] * o[1];
    *(f32x2*)&pst[RPC * D2 + row * D2 + c0] = oq;
  }
  __syncthreads();
  if (tid < D2) {
    float s = 0.f, q = 0.f;
#pragma unroll
    for (int g = 0; g < RPC; ++g) {
      s += pst[g * D2 + tid];
      q += pst[RPC * D2 + g * D2 + tid];
    }
    atomicAdd(acc1 + tid * AST, s);
    atomicAdd(acc1 + (128 + tid) * AST, q);
  }
}

// d (r18, unchanged): 256 blocks x 16 rows, LDS W2
__global__ __launch_bounds__(256) void d_kernel(
    const unsigned short* __restrict__ h1b, const float* __restrict__ W2,
    const float* __restrict__ b2, const float* __restrict__ g1,
    const float* __restrict__ be1, unsigned short* __restrict__ xb16,
    const float* __restrict__ acc1, float* __restrict__ acc2) {
  __shared__ float sW2[D2 * DD];
  __shared__ float sh1[RPB][D2 + 4];
  __shared__ float sS[D2], sB[D2];
  __shared__ float pst[2 * 8 * DD];
  int tid = threadIdx.x, bid = blockIdx.x;

  {
    const f32x4* w4 = (const f32x4*)W2;
    f32x4* s4 = (f32x4*)sW2;
#pragma unroll
    for (int i = 0; i < 8; ++i) s4[tid + i * 256] = w4[tid + i * 256];
  }
  if (tid < D2) {
    float mean = acc1[tid * AST] * (1.f / RTOT);
    float var = fmaf(-mean, mean, acc1[(128 + tid) * AST] * (1.f / RTOT));
    float sc = g1[tid] * rsqrtf(var + 1e-5f);
    sS[tid] = sc;
    sB[tid] = fmaf(-mean, sc, be1[tid]);
  }
  __syncthreads();
  {
    uint4 hv = ((const uint4*)(h1b + (size_t)bid * RPB * D2))[tid];
    int row = tid >> 4, cb = (tid & 15) * 8;
    unsigned w[4] = {hv.x, hv.y, hv.z, hv.w};
#pragma unroll
    for (int q = 0; q < 4; ++q) {
      float f0 = __uint_as_float(w[q] << 16);
      float f1 = __uint_as_float(w[q] & 0xFFFF0000u);
      int c = cb + 2 * q;
      sh1[row][c]     = fmaxf(fmaf(f0, sS[c],     sB[c]),     0.f);
      sh1[row][c + 1] = fmaxf(fmaf(f1, sS[c + 1], sB[c + 1]), 0.f);
    }
  }
  __syncthreads();

  float* pssum = pst;
  float* pssq  = pst + 8 * DD;
  if (tid < 128) {
    int rg = tid >> 4;
    int c0 = (tid & 15) * 4;
    f32x4 bv = *(const f32x4*)&b2[c0];
    f32x4 o0 = bv, o1 = bv;
    for (int c = 0; c < D2; c += 4) {
      f32x4 s0 = *(const f32x4*)&sh1[rg * 2 + 0][c];
      f32x4 s1 = *(const f32x4*)&sh1[rg * 2 + 1][c];
      f32x4 w0 = *(const f32x4*)&sW2[(c + 0) * DD + c0];
      f32x4 w1 = *(const f32x4*)&sW2[(c + 1) * DD + c0];
      f32x4 w2 = *(const f32x4*)&sW2[(c + 2) * DD + c0];
      f32x4 w3 = *(const f32x4*)&sW2[(c + 3) * DD + c0];
      fma4(o0, s0[0], w0); fma4(o0, s0[1], w1); fma4(o0, s0[2], w2); fma4(o0, s0[3], w3);
      fma4(o1, s1[0], w0); fma4(o1, s1[1], w1); fma4(o1, s1[2], w2); fma4(o1, s1[3], w3);
    }
    size_t gr = (size_t)(bid * RPB + rg * 2) * DD + c0;
    uint2 p0, p1;
    p0.x = f2b(o0[0]) | (f2b(o0[1]) << 16);
    p0.y = f2b(o0[2]) | (f2b(o0[3]) << 16);
    p1.x = f2b(o1[0]) | (f2b(o1[1]) << 16);
    p1.y = f2b(o1[2]) | (f2b(o1[3]) << 16);
    *(uint2*)&xb16[gr] = p0;
    *(uint2*)&xb16[gr + DD] = p1;
    *(f32x4*)&pssum[rg * DD + c0] = o0 + o1;
    *(f32x4*)&pssq[rg * DD + c0] = o0 * o0 + o1 * o1;
  }
  __syncthreads();
  if (tid < DD) {
    float s = 0.f, q = 0.f;
#pragma unroll
    for (int g = 0; g < 8; ++g) { s += pssum[g * DD + tid]; q += pssq[g * DD + tid]; }
    atomicAdd(acc2 + tid * AST, s);
    atomicAdd(acc2 + (64 + tid) * AST, q);
  }
}

// fin: BN2 (no relu) from padded acc, bf16 h2 -> fp32 out
__global__ __launch_bounds__(256) void fin_kernel(
    const unsigned short* __restrict__ xb16, const float* __restrict__ gbn,
    const float* __restrict__ bbn, const float* __restrict__ acc2,
    float* __restrict__ outp) {
  __shared__ float sS2[DD], sB2[DD];
  int tid = threadIdx.x, bid = blockIdx.x;
  if (tid < 64) {
    float mean = acc2[tid * AST] * (1.f / RTOT);
    float var = fmaf(-mean, mean, acc2[(64 + tid) * AST] * (1.f / RTOT));
    float sc = gbn[tid] * rsqrtf(var + 1e-5f);
    sS2[tid] = sc;
    sB2[tid] = fmaf(-mean, sc, bbn[tid]);
  }
  __syncthreads();
  {
    int g = bid * 256 + tid;
    uint2 v = ((const uint2*)xb16)[g];
    int e0 = g * 4;
    int c0 = e0 & 63;
    f32x4 o;
    o[0] = fmaf(__uint_as_float(v.x << 16),         sS2[c0],     sB2[c0]);
    o[1] = fmaf(__uint_as_float(v.x & 0xFFFF0000u), sS2[c0 + 1], sB2[c0 + 1]);
    o[2] = fmaf(__uint_as_float(v.y << 16),         sS2[c0 + 2], sB2[c0 + 2]);
    o[3] = fmaf(__uint_as_float(v.y & 0xFFFF0000u), sS2[c0 + 3], sB2[c0 + 3]);
    *(f32x4*)&outp[e0] = o;
  }
}

extern "C" void kernel_launch(void* const* d_in, const int* in_sizes, int n_in,
                              void* d_out, int out_size, void* d_ws, size_t ws_size,
                              hipStream_t stream) {
  const float* fea  = (const float*)d_in[0];
  const float* adj  = (const float*)d_in[1];
  const float* encW = (const float*)d_in[2];
  const float* encb = (const float*)d_in[3];
  const float* bondW= (const float*)d_in[4];
  const float* eps  = (const float*)d_in[5];
  const float* W1   = (const float*)d_in[6];
  const float* b1   = (const float*)d_in[7];
  const float* g1   = (const float*)d_in[8];
  const float* be1  = (const float*)d_in[9];
  const float* W2   = (const float*)d_in[10];
  const float* b2   = (const float*)d_in[11];
  const float* gbn  = (const float*)d_in[12];
  const float* bbn  = (const float*)d_in[13];
  float* out = (float*)d_out;
  float* ws  = (float*)d_ws;

  unsigned short* xb16 = (unsigned short*)ws;              // 262144 bf16
  unsigned short* h1b  = (unsigned short*)(ws + 131072);   // 524288 bf16
  float* acc = ws + 393216;                                // 49152 floats

  enc_kernel<<<512, 256, 0, stream>>>(fea, encW, encb, xb16, acc);
  for (int l = 0; l < 3; ++l) {
    float* accl = acc + (size_t)l * 512 * AST;
    bc_kernel<<<GBC, 512, 0, stream>>>(
        adj, xb16, bondW + l * DD, eps + l, W1 + l * DD * D2, b1 + l * D2,
        l ? gbn + (l - 1) * DD : gbn, l ? bbn + (l - 1) * DD : bbn,
        l ? acc + (size_t)(l - 1) * 512 * AST + 256 * AST : acc,
        l > 0 ? 1 : 0, h1b, accl);
    d_kernel<<<GBD, 256, 0, stream>>>(h1b, W2 + l * D2 * DD, b2 + l * DD,
                                      g1 + l * D2, be1 + l * D2, xb16,
                                      accl, accl + 256 * AST);
  }
  fin_kernel<<<256, 256, 0, stream>>>(xb16, gbn + 2 * DD, bbn + 2 * DD,
                                      acc + (size_t)2 * 512 * AST + 256 * AST, out);
}

// Round 21
// 85.124 us; speedup vs baseline: 2.5562x; 1.1049x over previous
//
#include <hip/hip_runtime.h>

#define NN 256
#define DIN 32
#define DD 64
#define D2 128
#define RTOT 4096      // BB*NN rows
#define GBD 256        // d/fin blocks
#define RPB 16         // rows per d block
#define GBC 512        // bc blocks
#define RPC 8          // rows per bc block
#define AST 32         // acc slot stride in floats (128 B line per channel)

typedef float f32x4 __attribute__((ext_vector_type(4)));
typedef float f32x2 __attribute__((ext_vector_type(2)));

__device__ __forceinline__ void fma4(f32x4& o, float s, const f32x4 w) {
  o[0] = fmaf(s, w[0], o[0]); o[1] = fmaf(s, w[1], o[1]);
  o[2] = fmaf(s, w[2], o[2]); o[3] = fmaf(s, w[3], o[3]);
}

__device__ __forceinline__ unsigned f2b(float f) {
  unsigned u = __float_as_uint(f);
  return (u + 0x7FFFu + ((u >> 16) & 1u)) >> 16;
}
__device__ __forceinline__ float b2f(unsigned short h) {
  return __uint_as_float(((unsigned)h) << 16);
}

// x(bf16) = fea @ encW + encb ; first 48 blocks zero the acc region.
// XCD-aligned: block sbid covers rows sbid*8.. so batch 2x/2x+1 -> XCD x,
// matching bc's consumer mapping (producer/consumer L2 locality).
__global__ __launch_bounds__(256) void enc_kernel(
    const float* __restrict__ fea, const float* __restrict__ W,
    const float* __restrict__ bias, unsigned short* __restrict__ xb16,
    float* __restrict__ accz) {
  if (blockIdx.x < 48) {
#pragma unroll
    for (int i = 0; i < 4; ++i)
      accz[blockIdx.x * 1024 + i * 256 + threadIdx.x] = 0.f;
  }
  const int sbid = ((blockIdx.x & 7) << 6) + (blockIdx.x >> 3);
  int g = sbid * 256 + threadIdx.x;
  int r = g >> 5, c0 = (g & 31) * 2;
  const float* fr = fea + r * DIN;
  float a0 = bias[c0], a1 = bias[c0 + 1];
#pragma unroll
  for (int k = 0; k < DIN; ++k) {
    float fv = fr[k];
    a0 = fmaf(fv, W[k * DD + c0], a0);
    a1 = fmaf(fv, W[k * DD + c0 + 1], a1);
  }
  ((unsigned*)xb16)[g] = f2b(a0) | (f2b(a1) << 16);
}

// bc (r18 verbatim): whole-batch Y (bf16) staged in LDS; ballot agg;
// MLP1 global-W1 -> h1 (bf16); padded fp32 BN1 stats. XCD affinity.
__global__ __launch_bounds__(256, 4) void bc_kernel(
    const float* __restrict__ adj, const unsigned short* __restrict__ xb16,
    const float* __restrict__ bondW, const float* __restrict__ epsp,
    const float* __restrict__ W1, const float* __restrict__ b1,
    const float* __restrict__ gbnp, const float* __restrict__ bbnp,
    const float* __restrict__ acc2p, int apply_bn,
    unsigned short* __restrict__ h1b, float* __restrict__ acc1) {
  __shared__ unsigned short sYb[NN * DD];
  __shared__ float sh[RPC * DD];
  __shared__ float sSB[2 * DD];
  float* pst = (float*)sYb;
  const int tid = threadIdx.x;
  const int sbid = ((blockIdx.x & 7) << 6) + (blockIdx.x >> 3);
  const int lane = tid & 63, wv = tid >> 6;
  const int b = sbid >> 5;
  const int r0 = (sbid & 31) * RPC;

  if (apply_bn && tid < DD) {
    float s = acc2p[tid * AST], q = acc2p[(64 + tid) * AST];
    float mean = s * (1.f / RTOT);
    float var = fmaf(-mean, mean, q * (1.f / RTOT));
    float sc = gbnp[tid] * rsqrtf(var + 1e-5f);
    sSB[tid] = sc;
    sSB[64 + tid] = fmaf(-mean, sc, bbnp[tid]);
  }
  __syncthreads();

  const unsigned short* xb = xb16 + (size_t)b * NN * DD;

  float a[2][4];
#pragma unroll
  for (int rr = 0; rr < 2; ++rr) {
    const float* adjr = adj + ((size_t)b * NN + r0 + wv * 2 + rr) * NN + lane;
#pragma unroll
    for (int ck = 0; ck < 4; ++ck) a[rr][ck] = adjr[ck * 64];
  }
  unsigned short xo[2];
#pragma unroll
  for (int rr = 0; rr < 2; ++rr)
    xo[rr] = xb[(size_t)(r0 + wv * 2 + rr) * DD + lane];
  uint4 yv[8];
  {
    const uint4* xb4 = (const uint4*)xb;
#pragma unroll
    for (int k = 0; k < 8; ++k) yv[k] = xb4[tid + k * 256];
  }

  unsigned long long m[2][4];
#pragma unroll
  for (int rr = 0; rr < 2; ++rr)
#pragma unroll
    for (int ck = 0; ck < 4; ++ck) m[rr][ck] = __ballot(a[rr][ck] != 0.f);

  {
    const int d0 = (tid & 7) * 8;
    float BW8[8], S8[8], B8[8];
#pragma unroll
    for (int j = 0; j < 8; ++j) {
      BW8[j] = bondW[d0 + j];
      S8[j] = apply_bn ? sSB[d0 + j] : 0.f;
      B8[j] = apply_bn ? sSB[64 + d0 + j] : 0.f;
    }
    uint4* sy4 = (uint4*)sYb;
#pragma unroll
    for (int k = 0; k < 8; ++k) {
      unsigned w[4] = {yv[k].x, yv[k].y, yv[k].z, yv[k].w};
      unsigned o[4];
#pragma unroll
      for (int q = 0; q < 4; ++q) {
        float f0 = __uint_as_float(w[q] << 16);
        float f1 = __uint_as_float(w[q] & 0xFFFF0000u);
        if (apply_bn) {
          f0 = fmaxf(fmaf(f0, S8[2 * q], B8[2 * q]), 0.f);
          f1 = fmaxf(fmaf(f1, S8[2 * q + 1], B8[2 * q + 1]), 0.f);
        }
        f0 = fmaxf(f0 + BW8[2 * q], 0.f);
        f1 = fmaxf(f1 + BW8[2 * q + 1], 0.f);
        o[q] = f2b(f0) | (f2b(f1) << 16);
      }
      sy4[tid + k * 256] = make_uint4(o[0], o[1], o[2], o[3]);
    }
  }
  __syncthreads();

  {
    float S = 0.f, Bv = 0.f;
    if (apply_bn) { S = sSB[lane]; Bv = sSB[64 + lane]; }
    float epv = 1.f + epsp[0];
#pragma unroll
    for (int rr = 0; rr < 2; ++rr) {
      float av = 0.f;
#pragma unroll
      for (int ck = 0; ck < 4; ++ck) {
        unsigned long long mm = m[rr][ck];
        const unsigned short* yb = sYb + ck * 64 * DD + lane;
        while (mm) {
          unsigned short v[8]; bool hb[8];
#pragma unroll
          for (int u = 0; u < 8; ++u) {
            bool ok = mm != 0ull;
            int j = ok ? (int)__builtin_ctzll(mm) : 0;
            mm &= mm - 1;
            hb[u] = ok;
            v[u] = yb[j * DD];
          }
#pragma unroll
          for (int u = 0; u < 8; ++u) av += hb[u] ? b2f(v[u]) : 0.f;
        }
      }
      float xv = b2f(xo[rr]);
      if (apply_bn) xv = fmaxf(fmaf(xv, S, Bv), 0.f);
      sh[(wv * 2 + rr) * DD + lane] = fmaf(epv, xv, av);
    }
  }
  __syncthreads();

  {
    int row = tid >> 5, c0 = (tid & 31) * 4;
    f32x4 o = *(const f32x4*)&b1[c0];
#pragma unroll 4
    for (int d = 0; d < DD; d += 4) {
      f32x4 hv = *(const f32x4*)&sh[row * DD + d];
      f32x4 w0 = *(const f32x4*)&W1[(d + 0) * D2 + c0];
      f32x4 w1 = *(const f32x4*)&W1[(d + 1) * D2 + c0];
      f32x4 w2 = *(const f32x4*)&W1[(d + 2) * D2 + c0];
      f32x4 w3 = *(const f32x4*)&W1[(d + 3) * D2 + c0];
      fma4(o, hv[0], w0); fma4(o, hv[1], w1); fma4(o, hv[2], w2); fma4(o, hv[3], w3);
    }
    uint2 hp;
    hp.x = f2b(o[0]) | (f2b(o[1]) << 16);
    hp.y = f2b(o[2]) | (f2b(o[3]) << 16);
    *(uint2*)&h1b[(size_t)(b * NN + r0 + row) * D2 + c0] = hp;
    *(f32x4*)&pst[row * D2 + c0] = o;
    *(f32x4*)&pst[RPC * D2 + row * D2 + c0] = o * o;
  }
  __syncthreads();
  if (tid < D2) {
    float s = 0.f, q = 0.f;
#pragma unroll
    for (int g = 0; g < RPC; ++g) {
      s += pst[g * D2 + tid];
      q += pst[RPC * D2 + g * D2 + tid];
    }
    atomicAdd(acc1 + tid * AST, s);
    atomicAdd(acc1 + (128 + tid) * AST, q);
  }
}

// d (r18 + XCD-aligned swizzle): 256 blocks x 16 rows, LDS W2.
// sbid mapping puts batch 2x/2x+1 rows on XCD x — same as bc/enc.
__global__ __launch_bounds__(256) void d_kernel(
    const unsigned short* __restrict__ h1b, const float* __restrict__ W2,
    const float* __restrict__ b2, const float* __restrict__ g1,
    const float* __restrict__ be1, unsigned short* __restrict__ xb16,
    const float* __restrict__ acc1, float* __restrict__ acc2) {
  __shared__ float sW2[D2 * DD];
  __shared__ float sh1[RPB][D2 + 4];
  __shared__ float sS[D2], sB[D2];
  __shared__ float pst[2 * 8 * DD];
  int tid = threadIdx.x;
  const int sbid = ((blockIdx.x & 7) << 5) + (blockIdx.x >> 3);

  {
    const f32x4* w4 = (const f32x4*)W2;
    f32x4* s4 = (f32x4*)sW2;
#pragma unroll
    for (int i = 0; i < 8; ++i) s4[tid + i * 256] = w4[tid + i * 256];
  }
  if (tid < D2) {
    float mean = acc1[tid * AST] * (1.f / RTOT);
    float var = fmaf(-mean, mean, acc1[(128 + tid) * AST] * (1.f / RTOT));
    float sc = g1[tid] * rsqrtf(var + 1e-5f);
    sS[tid] = sc;
    sB[tid] = fmaf(-mean, sc, be1[tid]);
  }
  __syncthreads();
  {
    uint4 hv = ((const uint4*)(h1b + (size_t)sbid * RPB * D2))[tid];
    int row = tid >> 4, cb = (tid & 15) * 8;
    unsigned w[4] = {hv.x, hv.y, hv.z, hv.w};
#pragma unroll
    for (int q = 0; q < 4; ++q) {
      float f0 = __uint_as_float(w[q] << 16);
      float f1 = __uint_as_float(w[q] & 0xFFFF0000u);
      int c = cb + 2 * q;
      sh1[row][c]     = fmaxf(fmaf(f0, sS[c],     sB[c]),     0.f);
      sh1[row][c + 1] = fmaxf(fmaf(f1, sS[c + 1], sB[c + 1]), 0.f);
    }
  }
  __syncthreads();

  float* pssum = pst;
  float* pssq  = pst + 8 * DD;
  if (tid < 128) {
    int rg = tid >> 4;
    int c0 = (tid & 15) * 4;
    f32x4 bv = *(const f32x4*)&b2[c0];
    f32x4 o0 = bv, o1 = bv;
    for (int c = 0; c < D2; c += 4) {
      f32x4 s0 = *(const f32x4*)&sh1[rg * 2 + 0][c];
      f32x4 s1 = *(const f32x4*)&sh1[rg * 2 + 1][c];
      f32x4 w0 = *(const f32x4*)&sW2[(c + 0) * DD + c0];
      f32x4 w1 = *(const f32x4*)&sW2[(c + 1) * DD + c0];
      f32x4 w2 = *(const f32x4*)&sW2[(c + 2) * DD + c0];
      f32x4 w3 = *(const f32x4*)&sW2[(c + 3) * DD + c0];
      fma4(o0, s0[0], w0); fma4(o0, s0[1], w1); fma4(o0, s0[2], w2); fma4(o0, s0[3], w3);
      fma4(o1, s1[0], w0); fma4(o1, s1[1], w1); fma4(o1, s1[2], w2); fma4(o1, s1[3], w3);
    }
    size_t gr = (size_t)(sbid * RPB + rg * 2) * DD + c0;
    uint2 p0, p1;
    p0.x = f2b(o0[0]) | (f2b(o0[1]) << 16);
    p0.y = f2b(o0[2]) | (f2b(o0[3]) << 16);
    p1.x = f2b(o1[0]) | (f2b(o1[1]) << 16);
    p1.y = f2b(o1[2]) | (f2b(o1[3]) << 16);
    *(uint2*)&xb16[gr] = p0;
    *(uint2*)&xb16[gr + DD] = p1;
    *(f32x4*)&pssum[rg * DD + c0] = o0 + o1;
    *(f32x4*)&pssq[rg * DD + c0] = o0 * o0 + o1 * o1;
  }
  __syncthreads();
  if (tid < DD) {
    float s = 0.f, q = 0.f;
#pragma unroll
    for (int g = 0; g < 8; ++g) { s += pssum[g * DD + tid]; q += pssq[g * DD + tid]; }
    atomicAdd(acc2 + tid * AST, s);
    atomicAdd(acc2 + (64 + tid) * AST, q);
  }
}

// fin: BN2 (no relu), bf16 h2 -> fp32 out; same XCD-aligned swizzle as d.
__global__ __launch_bounds__(256) void fin_kernel(
    const unsigned short* __restrict__ xb16, const float* __restrict__ gbn,
    const float* __restrict__ bbn, const float* __restrict__ acc2,
    float* __restrict__ outp) {
  __shared__ float sS2[DD], sB2[DD];
  int tid = threadIdx.x;
  const int sbid = ((blockIdx.x & 7) << 5) + (blockIdx.x >> 3);
  if (tid < 64) {
    float mean = acc2[tid * AST] * (1.f / RTOT);
    float var = fmaf(-mean, mean, acc2[(64 + tid) * AST] * (1.f / RTOT));
    float sc = gbn[tid] * rsqrtf(var + 1e-5f);
    sS2[tid] = sc;
    sB2[tid] = fmaf(-mean, sc, bbn[tid]);
  }
  __syncthreads();
  {
    int g = sbid * 256 + tid;
    uint2 v = ((const uint2*)xb16)[g];
    int e0 = g * 4;
    int c0 = e0 & 63;
    f32x4 o;
    o[0] = fmaf(__uint_as_float(v.x << 16),         sS2[c0],     sB2[c0]);
    o[1] = fmaf(__uint_as_float(v.x & 0xFFFF0000u), sS2[c0 + 1], sB2[c0 + 1]);
    o[2] = fmaf(__uint_as_float(v.y << 16),         sS2[c0 + 2], sB2[c0 + 2]);
    o[3] = fmaf(__uint_as_float(v.y & 0xFFFF0000u), sS2[c0 + 3], sB2[c0 + 3]);
    *(f32x4*)&outp[e0] = o;
  }
}

extern "C" void kernel_launch(void* const* d_in, const int* in_sizes, int n_in,
                              void* d_out, int out_size, void* d_ws, size_t ws_size,
                              hipStream_t stream) {
  const float* fea  = (const float*)d_in[0];
  const float* adj  = (const float*)d_in[1];
  const float* encW = (const float*)d_in[2];
  const float* encb = (const float*)d_in[3];
  const float* bondW= (const float*)d_in[4];
  const float* eps  = (const float*)d_in[5];
  const float* W1   = (const float*)d_in[6];
  const float* b1   = (const float*)d_in[7];
  const float* g1   = (const float*)d_in[8];
  const float* be1  = (const float*)d_in[9];
  const float* W2   = (const float*)d_in[10];
  const float* b2   = (const float*)d_in[11];
  const float* gbn  = (const float*)d_in[12];
  const float* bbn  = (const float*)d_in[13];
  float* out = (float*)d_out;
  float* ws  = (float*)d_ws;

  unsigned short* xb16 = (unsigned short*)ws;              // 262144 bf16
  unsigned short* h1b  = (unsigned short*)(ws + 131072);   // 524288 bf16
  float* acc = ws + 393216;                                // 49152 floats

  enc_kernel<<<512, 256, 0, stream>>>(fea, encW, encb, xb16, acc);
  for (int l = 0; l < 3; ++l) {
    float* accl = acc + (size_t)l * 512 * AST;
    bc_kernel<<<GBC, 256, 0, stream>>>(
        adj, xb16, bondW + l * DD, eps + l, W1 + l * DD * D2, b1 + l * D2,
        l ? gbn + (l - 1) * DD : gbn, l ? bbn + (l - 1) * DD : bbn,
        l ? acc + (size_t)(l - 1) * 512 * AST + 256 * AST : acc,
        l > 0 ? 1 : 0, h1b, accl);
    d_kernel<<<GBD, 256, 0, stream>>>(h1b, W2 + l * D2 * DD, b2 + l * DD,
                                      g1 + l * D2, be1 + l * D2, xb16,
                                      accl, accl + 256 * AST);
  }
  fin_kernel<<<256, 256, 0, stream>>>(xb16, gbn + 2 * DD, bbn + 2 * DD,
                                      acc + (size_t)2 * 512 * AST + 256 * AST, out);
}